// Round 12
// baseline (416.271 us; speedup 1.0000x reference)
//
#include <hip/hip_runtime.h>
#include <math.h>

#define B_ 2
#define S_ 4096
#define D_ 512
#define H_ 8
#define HD_ 64
#define NROW_ (B_ * S_)
#define NELEM_ ((size_t)NROW_ * D_)   // 4194304
#define WELEM_ ((size_t)D_ * D_)      // 262144

#define LOG2E_ 1.44269504f
#define SCLAMP_ 15.869645f   // 11 * log2(e): exp2(15.8696) = e^11 < 65504

typedef _Float16 half8 __attribute__((ext_vector_type(8)));
typedef _Float16 half4v __attribute__((ext_vector_type(4)));
typedef _Float16 half2v __attribute__((ext_vector_type(2)));
typedef __fp16 fp16x2 __attribute__((ext_vector_type(2)));   // pkrtz ret type
typedef float floatx4 __attribute__((ext_vector_type(4)));
typedef float floatx16 __attribute__((ext_vector_type(16)));
typedef int intx2 __attribute__((ext_vector_type(2)));
typedef unsigned uintx4 __attribute__((ext_vector_type(4)));

__device__ __forceinline__ half8 cvt_half8(float4 a, float4 b) {
  fp16x2 l0 = __builtin_amdgcn_cvt_pkrtz(a.x, a.y);
  fp16x2 l1 = __builtin_amdgcn_cvt_pkrtz(a.z, a.w);
  fp16x2 l2 = __builtin_amdgcn_cvt_pkrtz(b.x, b.y);
  fp16x2 l3 = __builtin_amdgcn_cvt_pkrtz(b.z, b.w);
  half8 h;
  h[0] = l0[0]; h[1] = l0[1]; h[2] = l1[0]; h[3] = l1[1];
  h[4] = l2[0]; h[5] = l2[1]; h[6] = l3[0]; h[7] = l3[1];
  return h;
}

// lane i <-> lane i+32 exchange: new_a = {a.lo, b.lo}, new_b = {a.hi, b.hi}
__device__ __forceinline__ void permswap32(unsigned& a, unsigned& b) {
#if __has_builtin(__builtin_amdgcn_permlane32_swap)
  intx2 r = __builtin_amdgcn_permlane32_swap((int)a, (int)b, false, false);
  a = (unsigned)r[0];
  b = (unsigned)r[1];
#else
  asm volatile("v_permlane32_swap_b32 %0, %1" : "+v"(a), "+v"(b));
#endif
}

// raw v_exp_f32: D = 2^x (log2e folded into Wq scale upstream)
__device__ __forceinline__ float exp2_hw(float x) {
  float r;
  asm("v_exp_f32 %0, %1" : "=v"(r) : "v"(x));
  return r;
}

// direct global->LDS 16B async copy; LDS dest must be wave-uniform
// (HW writes dest + lane*16); global src is per-lane.
typedef const unsigned __attribute__((address_space(1))) gu32_t;
typedef unsigned __attribute__((address_space(3))) lu32_t;
__device__ __forceinline__ void gload16(const void* g, void* l) {
  __builtin_amdgcn_global_load_lds((gu32_t*)g, (lu32_t*)l, 16, 0, 0);
}

// ---------------------------------------------------------------------------
// prep: (a) W[512][512] fp32 -> W^T fp16 (scaled), 4 weights (units 0..1023);
//       (b) x,y fp32 -> fp16 Xh (units 1024..2047).
// ---------------------------------------------------------------------------
struct PrepPtrs { const float *W0, *W1, *W2, *W3, *X0, *X1; };

__global__ __launch_bounds__(256) void prep_kernel(
    PrepPtrs p, _Float16* __restrict__ WTbase, _Float16* __restrict__ Xh) {
  __shared__ float tl[32][33];
  const int bid = blockIdx.x;
  const int t = threadIdx.x;
  if (bid < 1024) {
    const int z = bid >> 8, r8 = bid & 255;
    const int bx = r8 & 15, by = r8 >> 4;
    const float* W = z == 0 ? p.W0 : z == 1 ? p.W1 : z == 2 ? p.W2 : p.W3;
    const float scale = z == 0 ? 0.125f * LOG2E_ : 1.0f;
    _Float16* Wt = WTbase + (size_t)z * WELEM_;
    const int k0 = by * 32, n0 = bx * 32;
    const int r = t >> 3, c0 = (t & 7) * 4;
    const float4 v = *(const float4*)&W[(size_t)(k0 + r) * D_ + n0 + c0];
    tl[r][c0 + 0] = v.x; tl[r][c0 + 1] = v.y;
    tl[r][c0 + 2] = v.z; tl[r][c0 + 3] = v.w;
    __syncthreads();
    half4v hv;
#pragma unroll
    for (int j = 0; j < 4; ++j) hv[j] = (_Float16)(tl[c0 + j][r] * scale);
    *(half4v*)&Wt[(size_t)(n0 + r) * D_ + k0 + c0] = hv;
  } else {
    const int cid = bid - 1024;                  // 0..1023
    const size_t e0 = (size_t)cid * 8192;
    const float* src = e0 < NELEM_ ? p.X0 + e0 : p.X1 + (e0 - NELEM_);
    _Float16* dst = Xh + e0;
    const float4* s4 = (const float4*)src;
#pragma unroll
    for (int j = 0; j < 4; ++j) {
      const int i8 = j * 256 + t;                // half8 index within chunk
      const float4 a = s4[2 * i8];
      const float4 b = s4[2 * i8 + 1];
      *(half8*)&dst[(size_t)i8 * 8] = cvt_half8(a, b);
    }
  }
}

// ---------------------------------------------------------------------------
// MFMA GEMM body (unchanged from round 11 — see r8/r9 notes).
// ---------------------------------------------------------------------------
template <bool AF16, int OUTMODE, int BM, bool GL>
__device__ __forceinline__ void gemm_body(
    const void* __restrict__ Av, const _Float16* __restrict__ Bt,
    const float* __restrict__ bias, void* __restrict__ Cout, float bscale,
    _Float16* pool, int bx, int by, int tid) {
  constexpr int MT = BM / 32;   // 16-row tiles per wave
  const int w = tid >> 6, lane = tid & 63;
  const int m = lane & 15, quad = lane >> 4;
  const int row0 = by * BM, col0 = bx * 128;
  const int wr = (w >> 1) * (BM / 2), wc = (w & 1) * 64;

  const _Float16* A16 = (const _Float16*)Av;
  const float* A32 = (const float*)Av;

  floatx4 acc[MT][4];
#pragma unroll
  for (int i = 0; i < MT; ++i)
#pragma unroll
    for (int j = 0; j < 4; ++j) acc[i][j] = floatx4{0.f, 0.f, 0.f, 0.f};

  if constexpr (GL) {
    _Float16 (*Asl)[64] = (_Float16 (*)[64])pool;
    _Float16 (*Bsl)[64] = (_Float16 (*)[64])(pool + BM * 64);
    for (int kt = 0; kt < D_ / 64; ++kt) {
      if (kt) __syncthreads();
      const int kc = kt * 64;
#pragma unroll
      for (int i = 0; i < BM / 32; ++i) {
        const int rb = (i * 4 + w) * 8;
        const int row = rb + (lane >> 3);
        const int slot = (lane & 7) ^ (row & 7);
        gload16(&A16[(size_t)(row0 + row) * D_ + kc + slot * 8], &Asl[rb][0]);
      }
#pragma unroll
      for (int i = 0; i < 4; ++i) {
        const int rb = (i * 4 + w) * 8;
        const int row = rb + (lane >> 3);
        const int slot = (lane & 7) ^ (row & 7);
        gload16(&Bt[(size_t)(col0 + row) * D_ + kc + slot * 8], &Bsl[rb][0]);
      }
      __syncthreads();   // drains vmcnt (glLDS) + rendezvous
#pragma unroll
      for (int h = 0; h < 2; ++h) {
        half8 af[MT], bf[4];
#pragma unroll
        for (int mt = 0; mt < MT; ++mt) {
          const int r = wr + mt * 16 + m;
          af[mt] = *(const half8*)&Asl[r][(((4 * h + quad) ^ (r & 7)) * 8)];
        }
#pragma unroll
        for (int nt = 0; nt < 4; ++nt) {
          const int r = wc + nt * 16 + m;
          bf[nt] = *(const half8*)&Bsl[r][(((4 * h + quad) ^ (r & 7)) * 8)];
        }
#pragma unroll
        for (int mt = 0; mt < MT; ++mt)
#pragma unroll
          for (int nt = 0; nt < 4; ++nt)
            acc[mt][nt] = __builtin_amdgcn_mfma_f32_16x16x32_f16(
                af[mt], bf[nt], acc[mt][nt], 0, 0, 0);
      }
    }
  } else {
    _Float16 (*As)[72] = (_Float16 (*)[72])pool;
    _Float16 (*Bs)[72] = (_Float16 (*)[72])(pool + BM * 72);
    const int srow = tid >> 3, soff = (tid & 7) * 8;

    half8 pa16[MT];
    float4 pa32[MT][2];
    half8 pb[4];
#pragma unroll
    for (int i = 0; i < MT; ++i) {
      const size_t ar = (size_t)(row0 + srow + 32 * i) * D_ + soff;
      if (AF16) pa16[i] = *(const half8*)&A16[ar];
      else { pa32[i][0] = *(const float4*)&A32[ar];
             pa32[i][1] = *(const float4*)&A32[ar + 4]; }
    }
#pragma unroll
    for (int i = 0; i < 4; ++i)
      pb[i] = *(const half8*)&Bt[(size_t)(col0 + srow + 32 * i) * D_ + soff];

    for (int kt = 0; kt < D_ / 64; ++kt) {
      if (kt) __syncthreads();
#pragma unroll
      for (int i = 0; i < MT; ++i)
        *(half8*)&As[srow + 32 * i][soff] =
            AF16 ? pa16[i] : cvt_half8(pa32[i][0], pa32[i][1]);
#pragma unroll
      for (int i = 0; i < 4; ++i) *(half8*)&Bs[srow + 32 * i][soff] = pb[i];
      __syncthreads();
      if (kt < D_ / 64 - 1) {
        const int kc = (kt + 1) * 64 + soff;
#pragma unroll
        for (int i = 0; i < MT; ++i) {
          const size_t ar = (size_t)(row0 + srow + 32 * i) * D_ + kc;
          if (AF16) pa16[i] = *(const half8*)&A16[ar];
          else { pa32[i][0] = *(const float4*)&A32[ar];
                 pa32[i][1] = *(const float4*)&A32[ar + 4]; }
        }
#pragma unroll
        for (int i = 0; i < 4; ++i)
          pb[i] = *(const half8*)&Bt[(size_t)(col0 + srow + 32 * i) * D_ + kc];
      }
#pragma unroll
      for (int h = 0; h < 2; ++h) {
        half8 af[MT], bf[4];
#pragma unroll
        for (int mt = 0; mt < MT; ++mt)
          af[mt] = *(const half8*)&As[wr + mt * 16 + m][h * 32 + quad * 8];
#pragma unroll
        for (int nt = 0; nt < 4; ++nt)
          bf[nt] = *(const half8*)&Bs[wc + nt * 16 + m][h * 32 + quad * 8];
#pragma unroll
        for (int mt = 0; mt < MT; ++mt)
#pragma unroll
          for (int nt = 0; nt < 4; ++nt)
            acc[mt][nt] = __builtin_amdgcn_mfma_f32_16x16x32_f16(
                af[mt], bf[nt], acc[mt][nt], 0, 0, 0);
      }
    }
  }

  float bv[4];
#pragma unroll
  for (int nt = 0; nt < 4; ++nt)
    bv[nt] = bias[col0 + wc + nt * 16 + m] * bscale;

  if constexpr (OUTMODE == 2) {
    // ---- transposed V store: C tile -> LDS -> VhT[b][h][d][s] ----
    __syncthreads();   // all frag reads of As/Bs done before alias
    _Float16 (*Ct)[132] = (_Float16 (*)[132])pool;   // 128x132 <= pool
#pragma unroll
    for (int mt = 0; mt < MT; ++mt)
#pragma unroll
      for (int nt = 0; nt < 4; ++nt)
#pragma unroll
        for (int r = 0; r < 4; ++r)
          Ct[wr + mt * 16 + quad * 4 + r][wc + nt * 16 + m] =
              (_Float16)(acc[mt][nt][r] + bv[nt]);
    __syncthreads();
    const int c = tid & 127, sc = tid >> 7;          // col, s-half
    const int head = (col0 + c) >> 6, dd = (col0 + c) & 63;
    const int b = row0 >> 12;
    const int sbase = (row0 & (S_ - 1)) + sc * 64;
    _Float16* dst = (_Float16*)Cout +
        ((size_t)(b * H_ + head) * HD_ + dd) * S_ + sbase;
#pragma unroll
    for (int j = 0; j < 8; ++j) {
      half8 o;
#pragma unroll
      for (int e = 0; e < 8; ++e) o[e] = Ct[sc * 64 + j * 8 + e][c];
      *(half8*)&dst[j * 8] = o;
    }
  } else {
#pragma unroll
    for (int mt = 0; mt < MT; ++mt)
#pragma unroll
      for (int nt = 0; nt < 4; ++nt)
#pragma unroll
        for (int r = 0; r < 4; ++r) {
          const int row = row0 + wr + mt * 16 + quad * 4 + r;
          const int col = col0 + wc + nt * 16 + m;
          const float vout = acc[mt][nt][r] + bv[nt];
          if (OUTMODE == 1)
            ((_Float16*)Cout)[(size_t)row * D_ + col] = (_Float16)vout;
          else
            ((float*)Cout)[(size_t)row * D_ + col] = vout;
        }
  }
}

struct QkvPtrs { const float *A2, *b0, *b1, *b2; };

__global__ __launch_bounds__(256, 3) void qkv_gemm_kernel(
    QkvPtrs p, const _Float16* __restrict__ WT, _Float16* __restrict__ Cb,
    _Float16* __restrict__ VhT, const _Float16* __restrict__ Xh) {
  __shared__ alignas(16) _Float16 pool[(128 + 128) * 72];
  const int z = blockIdx.z;
  if (z == 2)
    gemm_body<false, 2, 128, false>(p.A2, WT + 2 * WELEM_, p.b2, VhT, 1.0f,
                                    pool, blockIdx.x, blockIdx.y, threadIdx.x);
  else
    gemm_body<true, 1, 128, true>(Xh + (size_t)z * NELEM_,
                                  WT + (size_t)z * WELEM_,
                                  z == 0 ? p.b0 : p.b1, Cb + (size_t)z * NELEM_,
                                  z == 0 ? 0.125f * LOG2E_ : 1.0f, pool,
                                  blockIdx.x, blockIdx.y, threadIdx.x);
}

// BM=32: 1024 blocks (grid 4x256) at 4 blocks/CU (r11: small win, keep).
__global__ __launch_bounds__(256, 4) void out_gemm_kernel(
    const _Float16* __restrict__ Oh, const _Float16* __restrict__ WpT,
    const float* __restrict__ bp, float* __restrict__ out) {
  __shared__ alignas(16) _Float16 pool[(32 + 128) * 72];
  gemm_body<true, 0, 32, true>(Oh, WpT, bp, out, 1.0f, pool, blockIdx.x,
                               blockIdx.y, threadIdx.x);
}

// ---------------------------------------------------------------------------
// MFMA flash attention, 32x32x16, fp16 I/O, split-K over keys — now with a
// 1-tile-deep QK/softmax software pipeline (T15 mechanism):
//   body(t): stage t+1 -> B1 -> QK(t+1)->sNext -> prefetch t+2
//            -> softmax+PV(t) from sPrev -> B2
// QK(t+1)'s MFMA/ds_read stream overlaps softmax(t)'s VALU stream IN-WAVE
// (counters show issue port ~60% — latency-bound, not issue-bound).
// Named sA/sB roles via x2-unrolled loop (rule #20: no runtime acc index).
// lpart via v_dot2_f32_f16 on the packed fp16 P pair (halves the adds;
// denominator now uses the same fp16-rounded values as the PV numerator).
// ---------------------------------------------------------------------------
__global__ __launch_bounds__(512, 4) void attn_mfma_kernel(
    const _Float16* __restrict__ Qg, const _Float16* __restrict__ Kg,
    const _Float16* __restrict__ VT, _Float16* __restrict__ Og) {
  __shared__ alignas(16) unsigned char smem[73728];
  _Float16 (*Ks)[2][64][72] =
      reinterpret_cast<_Float16 (*)[2][64][72]>(smem);          // [g][buf][key][d]
  _Float16 (*Vt)[2][64][72] =
      reinterpret_cast<_Float16 (*)[2][64][72]>(smem + 36864);  // [g][buf][d][key]
  float (*comb)[64][36] = (float (*)[64][36])smem;              // epilogue alias

  const int t = threadIdx.x;
  const int w = t >> 6;            // 0..7
  const int g = w >> 2;            // key-group
  const int wq = w & 3;            // wave within group
  const int lane = t & 63;
  const int li = lane & 31;        // q (B-side col) / key- or d-row (A-side)
  const int hl = lane >> 5;        // half-wave
  const int q0 = blockIdx.x * 128 + wq * 32;
  const int koff = g * (S_ / 2);
  const size_t base =
      (size_t)blockIdx.z * ((size_t)S_ * D_) + (size_t)blockIdx.y * HD_;
  const size_t vbase = (size_t)(blockIdx.z * H_ + blockIdx.y) * HD_ * S_;

  // Q B-frags: qb[ks][j] = Q[q0+li][16ks + 8hl + j]
  half8 qb[4];
#pragma unroll
  for (int ks = 0; ks < 4; ++ks)
    qb[ks] = *(const half8*)
        &Qg[base + (size_t)(q0 + li) * D_ + ks * 16 + hl * 8];

  floatx16 oacc[2];
#pragma unroll
  for (int i = 0; i < 16; ++i) { oacc[0][i] = 0.f; oacc[1][i] = 0.f; }
  float lpart = 0.f;
  const half2v one2 = {(_Float16)1.0f, (_Float16)1.0f};

  const int tg = t & 255;          // staging id within the group
  const int srow = tg >> 3, soff = (tg & 7) * 8;

  half8 pk[2], pv[2];

  auto load_regs = [&](int tile) {
    const int k2 = koff + tile * 64;
#pragma unroll
    for (int i = 0; i < 2; ++i) {
      pk[i] = *(const half8*)
          &Kg[base + (size_t)(k2 + srow + 32 * i) * D_ + soff];
      pv[i] = *(const half8*)
          &VT[vbase + (size_t)(srow + 32 * i) * S_ + k2 + soff];
    }
  };
  auto stage_regs = [&](int buf) {
#pragma unroll
    for (int i = 0; i < 2; ++i) {
      *(half8*)&Ks[g][buf][srow + 32 * i][soff] = pk[i];
      *(half8*)&Vt[g][buf][srow + 32 * i][soff] = pv[i];
    }
  };
  auto qk_tile = [&](floatx16 (&s)[2], int buf) {
#pragma unroll
    for (int i = 0; i < 16; ++i) { s[0][i] = 0.f; s[1][i] = 0.f; }
    __builtin_amdgcn_s_setprio(1);
#pragma unroll
    for (int ks = 0; ks < 4; ++ks) {
      const half8 ka0 = *(const half8*)&Ks[g][buf][li][ks * 16 + hl * 8];
      const half8 ka1 = *(const half8*)&Ks[g][buf][32 + li][ks * 16 + hl * 8];
      s[0] = __builtin_amdgcn_mfma_f32_32x32x16_f16(ka0, qb[ks], s[0],
                                                    0, 0, 0);
      s[1] = __builtin_amdgcn_mfma_f32_32x32x16_f16(ka1, qb[ks], s[1],
                                                    0, 0, 0);
    }
    __builtin_amdgcn_s_setprio(0);
  };
  auto smpv_tile = [&](floatx16 (&s)[2], int buf) {
    // source reg r of s[kt2] holds key-local (r&3)+8*(r>>2)+4*hl;
    // target frag(ks=2kt2+t2) half j needs key-local 16t2+8hl+j.
#pragma unroll
    for (int kt2 = 0; kt2 < 2; ++kt2) {
      unsigned dq[4][2];
#pragma unroll
      for (int rq = 0; rq < 4; ++rq)
#pragma unroll
        for (int pp = 0; pp < 2; ++pp) {
          const float e0 = exp2_hw(fminf(s[kt2][4 * rq + 2 * pp], SCLAMP_));
          const float e1 =
              exp2_hw(fminf(s[kt2][4 * rq + 2 * pp + 1], SCLAMP_));
          const fp16x2 h2 = __builtin_amdgcn_cvt_pkrtz(e0, e1);
#if __has_builtin(__builtin_amdgcn_fdot2)
          lpart = __builtin_amdgcn_fdot2(__builtin_bit_cast(half2v, h2),
                                         one2, lpart, false);
#else
          lpart += e0 + e1;
#endif
          dq[rq][pp] = __builtin_bit_cast(unsigned, h2);
        }
      half8 pf[2];
#pragma unroll
      for (int t2 = 0; t2 < 2; ++t2) {
        unsigned a0 = dq[2 * t2][0], b0 = dq[2 * t2 + 1][0];
        unsigned a1 = dq[2 * t2][1], b1 = dq[2 * t2 + 1][1];
        permswap32(a0, b0);
        permswap32(a1, b1);
        uintx4 u; u[0] = a0; u[1] = a1; u[2] = b0; u[3] = b1;
        pf[t2] = __builtin_bit_cast(half8, u);
      }
      __builtin_amdgcn_s_setprio(1);
#pragma unroll
      for (int t2 = 0; t2 < 2; ++t2) {
        const int ks = 2 * kt2 + t2;
        const half8 va0 = *(const half8*)&Vt[g][buf][li][ks * 16 + hl * 8];
        const half8 va1 =
            *(const half8*)&Vt[g][buf][32 + li][ks * 16 + hl * 8];
        oacc[0] = __builtin_amdgcn_mfma_f32_32x32x16_f16(va0, pf[t2],
                                                         oacc[0], 0, 0, 0);
        oacc[1] = __builtin_amdgcn_mfma_f32_32x32x16_f16(va1, pf[t2],
                                                         oacc[1], 0, 0, 0);
      }
      __builtin_amdgcn_s_setprio(0);
    }
  };

  // ---- prologue: stage tile 0 -> buf0, tile 1 -> regs, QK(0) ----
#pragma unroll
  for (int i = 0; i < 2; ++i) {
    *(half8*)&Ks[g][0][srow + 32 * i][soff] = *(const half8*)
        &Kg[base + (size_t)(koff + srow + 32 * i) * D_ + soff];
    *(half8*)&Vt[g][0][srow + 32 * i][soff] = *(const half8*)
        &VT[vbase + (size_t)(srow + 32 * i) * S_ + koff + soff];
  }
  load_regs(1);
  __syncthreads();

  floatx16 sA[2], sB[2];
  qk_tile(sA, 0);

  constexpr int NT2 = S_ / 128;    // 32 tiles per key-group (even)
  for (int kt = 0; kt < NT2; kt += 2) {
    {  // tile kt (buf 0, acc sA); pipeline QK(kt+1) into sB
      const int tt = kt;
      if (tt + 1 < NT2) {
        stage_regs(1);
        __syncthreads();                       // B1: tile tt+1 visible
        qk_tile(sB, 1);
        if (tt + 2 < NT2) load_regs(tt + 2);
      }
      smpv_tile(sA, 0);
      __syncthreads();                         // B2: frees buf 0
    }
    {  // tile kt+1 (buf 1, acc sB); pipeline QK(kt+2) into sA
      const int tt = kt + 1;
      if (tt + 1 < NT2) {
        stage_regs(0);
        __syncthreads();                       // B1: tile tt+1 visible
        qk_tile(sA, 0);
        if (tt + 2 < NT2) load_regs(tt + 2);
      }
      smpv_tile(sB, 1);
      __syncthreads();                         // B2: frees buf 1
    }
  }

  // within-group full row-sum: lanes l and l+32 hold disjoint key subsets
  const float wsum = lpart + __shfl_xor(lpart, 32);

  // ---- cross-group combine (partials additive: clamp-softmax) ----
  if (g == 1) {
#pragma unroll
    for (int n = 0; n < 2; ++n)
#pragma unroll
      for (int c = 0; c < 4; ++c) {
        float4 f;
        f.x = oacc[n][4 * c + 0]; f.y = oacc[n][4 * c + 1];
        f.z = oacc[n][4 * c + 2]; f.w = oacc[n][4 * c + 3];
        *(float4*)&comb[wq][lane][n * 16 + 4 * c] = f;
      }
    comb[wq][lane][32] = wsum;
  }
  __syncthreads();
  if (g == 0) {
    const float linv = 1.0f / (wsum + comb[wq][lane][32]);
    // C[d][q]: lane q = li fixed; d = 32n + 8rq + (r&3) + 4hl
#pragma unroll
    for (int n = 0; n < 2; ++n)
#pragma unroll
      for (int rq = 0; rq < 4; ++rq) {
        const float4 cf = *(const float4*)&comb[wq][lane][n * 16 + 4 * rq];
        half4v o4;
        o4[0] = (_Float16)((oacc[n][4 * rq + 0] + cf.x) * linv);
        o4[1] = (_Float16)((oacc[n][4 * rq + 1] + cf.y) * linv);
        o4[2] = (_Float16)((oacc[n][4 * rq + 2] + cf.z) * linv);
        o4[3] = (_Float16)((oacc[n][4 * rq + 3] + cf.w) * linv);
        *(half4v*)&Og[base + (size_t)(q0 + li) * D_ +
                      n * 32 + 8 * rq + 4 * hl] = o4;
      }
  }
}

// ---------------------------------------------------------------------------
extern "C" void kernel_launch(void* const* d_in, const int* in_sizes, int n_in,
                              void* d_out, int out_size, void* d_ws,
                              size_t ws_size, hipStream_t stream) {
  const float* x  = (const float*)d_in[0];
  const float* y  = (const float*)d_in[1];
  const float* z  = (const float*)d_in[2];
  const float* Wq = (const float*)d_in[3];
  const float* bq = (const float*)d_in[4];
  const float* Wk = (const float*)d_in[5];
  const float* bk = (const float*)d_in[6];
  const float* Wv = (const float*)d_in[7];
  const float* bv = (const float*)d_in[8];
  const float* Wp = (const float*)d_in[9];
  const float* bp = (const float*)d_in[10];

  // workspace layout (44.04 MB, known-good footprint):
  //   WT  : 4 x WELEM                      (W^T fp16, q/k/v/p)
  //   Xh  : 2 x NELEM  (x,y fp16)  -- dead after qkv; Oh aliases it
  //   Qh, Kh, VhT : 1 x NELEM each
  _Float16* hws = (_Float16*)d_ws;
  _Float16* WT  = hws;
  _Float16* Xh  = WT + 4 * WELEM_;
  _Float16* Qh  = Xh + 2 * NELEM_;
  _Float16* Kh  = Qh + NELEM_;
  _Float16* VhT = Kh + NELEM_;
  _Float16* Oh  = Xh;                       // alias: Xh dead before attn

  PrepPtrs pp{Wq, Wk, Wv, Wp, x, y};
  prep_kernel<<<dim3(2048), 256, 0, stream>>>(pp, WT, Xh);

  QkvPtrs qp{z, bq, bk, bv};
  qkv_gemm_kernel<<<dim3(4, 64, 3), 256, 0, stream>>>(qp, WT, Qh, VhT, Xh);

  attn_mfma_kernel<<<dim3(S_ / 128, H_, B_), 512, 0, stream>>>(Qh, Kh, VhT, Oh);

  out_gemm_kernel<<<dim3(4, 256), 256, 0, stream>>>(Oh, WT + 3 * WELEM_, bp,
                                                    (float*)d_out);
}

// Round 13
// 234.942 us; speedup vs baseline: 1.7718x; 1.7718x over previous
//
#include <hip/hip_runtime.h>
#include <math.h>

#define B_ 2
#define S_ 4096
#define D_ 512
#define H_ 8
#define HD_ 64
#define NROW_ (B_ * S_)
#define NELEM_ ((size_t)NROW_ * D_)   // 4194304
#define WELEM_ ((size_t)D_ * D_)      // 262144

#define LOG2E_ 1.44269504f
#define SCLAMP_ 15.869645f   // 11 * log2(e): exp2(15.8696) = e^11 < 65504

typedef _Float16 half8 __attribute__((ext_vector_type(8)));
typedef _Float16 half4v __attribute__((ext_vector_type(4)));
typedef _Float16 half2v __attribute__((ext_vector_type(2)));
typedef __fp16 fp16x2 __attribute__((ext_vector_type(2)));   // pkrtz ret type
typedef float floatx4 __attribute__((ext_vector_type(4)));
typedef float floatx16 __attribute__((ext_vector_type(16)));
typedef int intx2 __attribute__((ext_vector_type(2)));
typedef unsigned uintx4 __attribute__((ext_vector_type(4)));

__device__ __forceinline__ half8 cvt_half8(float4 a, float4 b) {
  fp16x2 l0 = __builtin_amdgcn_cvt_pkrtz(a.x, a.y);
  fp16x2 l1 = __builtin_amdgcn_cvt_pkrtz(a.z, a.w);
  fp16x2 l2 = __builtin_amdgcn_cvt_pkrtz(b.x, b.y);
  fp16x2 l3 = __builtin_amdgcn_cvt_pkrtz(b.z, b.w);
  half8 h;
  h[0] = l0[0]; h[1] = l0[1]; h[2] = l1[0]; h[3] = l1[1];
  h[4] = l2[0]; h[5] = l2[1]; h[6] = l3[0]; h[7] = l3[1];
  return h;
}

// lane i <-> lane i+32 exchange: new_a = {a.lo, b.lo}, new_b = {a.hi, b.hi}
__device__ __forceinline__ void permswap32(unsigned& a, unsigned& b) {
#if __has_builtin(__builtin_amdgcn_permlane32_swap)
  intx2 r = __builtin_amdgcn_permlane32_swap((int)a, (int)b, false, false);
  a = (unsigned)r[0];
  b = (unsigned)r[1];
#else
  asm volatile("v_permlane32_swap_b32 %0, %1" : "+v"(a), "+v"(b));
#endif
}

// raw v_exp_f32: D = 2^x (log2e folded into Wq scale upstream)
__device__ __forceinline__ float exp2_hw(float x) {
  float r;
  asm("v_exp_f32 %0, %1" : "=v"(r) : "v"(x));
  return r;
}

// direct global->LDS 16B async copy; LDS dest must be wave-uniform
// (HW writes dest + lane*16); global src is per-lane.
typedef const unsigned __attribute__((address_space(1))) gu32_t;
typedef unsigned __attribute__((address_space(3))) lu32_t;
__device__ __forceinline__ void gload16(const void* g, void* l) {
  __builtin_amdgcn_global_load_lds((gu32_t*)g, (lu32_t*)l, 16, 0, 0);
}

// ---------------------------------------------------------------------------
// prep: (a) W[512][512] fp32 -> W^T fp16 (scaled), 4 weights (units 0..1023);
//       (b) x,y fp32 -> fp16 Xh (units 1024..2047).
// ---------------------------------------------------------------------------
struct PrepPtrs { const float *W0, *W1, *W2, *W3, *X0, *X1; };

__global__ __launch_bounds__(256) void prep_kernel(
    PrepPtrs p, _Float16* __restrict__ WTbase, _Float16* __restrict__ Xh) {
  __shared__ float tl[32][33];
  const int bid = blockIdx.x;
  const int t = threadIdx.x;
  if (bid < 1024) {
    const int z = bid >> 8, r8 = bid & 255;
    const int bx = r8 & 15, by = r8 >> 4;
    const float* W = z == 0 ? p.W0 : z == 1 ? p.W1 : z == 2 ? p.W2 : p.W3;
    const float scale = z == 0 ? 0.125f * LOG2E_ : 1.0f;
    _Float16* Wt = WTbase + (size_t)z * WELEM_;
    const int k0 = by * 32, n0 = bx * 32;
    const int r = t >> 3, c0 = (t & 7) * 4;
    const float4 v = *(const float4*)&W[(size_t)(k0 + r) * D_ + n0 + c0];
    tl[r][c0 + 0] = v.x; tl[r][c0 + 1] = v.y;
    tl[r][c0 + 2] = v.z; tl[r][c0 + 3] = v.w;
    __syncthreads();
    half4v hv;
#pragma unroll
    for (int j = 0; j < 4; ++j) hv[j] = (_Float16)(tl[c0 + j][r] * scale);
    *(half4v*)&Wt[(size_t)(n0 + r) * D_ + k0 + c0] = hv;
  } else {
    const int cid = bid - 1024;                  // 0..1023
    const size_t e0 = (size_t)cid * 8192;
    const float* src = e0 < NELEM_ ? p.X0 + e0 : p.X1 + (e0 - NELEM_);
    _Float16* dst = Xh + e0;
    const float4* s4 = (const float4*)src;
#pragma unroll
    for (int j = 0; j < 4; ++j) {
      const int i8 = j * 256 + t;                // half8 index within chunk
      const float4 a = s4[2 * i8];
      const float4 b = s4[2 * i8 + 1];
      *(half8*)&dst[(size_t)i8 * 8] = cvt_half8(a, b);
    }
  }
}

// ---------------------------------------------------------------------------
// MFMA GEMM body (unchanged from round 11 — see r8/r9 notes).
// ---------------------------------------------------------------------------
template <bool AF16, int OUTMODE, int BM, bool GL>
__device__ __forceinline__ void gemm_body(
    const void* __restrict__ Av, const _Float16* __restrict__ Bt,
    const float* __restrict__ bias, void* __restrict__ Cout, float bscale,
    _Float16* pool, int bx, int by, int tid) {
  constexpr int MT = BM / 32;   // 16-row tiles per wave
  const int w = tid >> 6, lane = tid & 63;
  const int m = lane & 15, quad = lane >> 4;
  const int row0 = by * BM, col0 = bx * 128;
  const int wr = (w >> 1) * (BM / 2), wc = (w & 1) * 64;

  const _Float16* A16 = (const _Float16*)Av;
  const float* A32 = (const float*)Av;

  floatx4 acc[MT][4];
#pragma unroll
  for (int i = 0; i < MT; ++i)
#pragma unroll
    for (int j = 0; j < 4; ++j) acc[i][j] = floatx4{0.f, 0.f, 0.f, 0.f};

  if constexpr (GL) {
    _Float16 (*Asl)[64] = (_Float16 (*)[64])pool;
    _Float16 (*Bsl)[64] = (_Float16 (*)[64])(pool + BM * 64);
    for (int kt = 0; kt < D_ / 64; ++kt) {
      if (kt) __syncthreads();
      const int kc = kt * 64;
#pragma unroll
      for (int i = 0; i < BM / 32; ++i) {
        const int rb = (i * 4 + w) * 8;
        const int row = rb + (lane >> 3);
        const int slot = (lane & 7) ^ (row & 7);
        gload16(&A16[(size_t)(row0 + row) * D_ + kc + slot * 8], &Asl[rb][0]);
      }
#pragma unroll
      for (int i = 0; i < 4; ++i) {
        const int rb = (i * 4 + w) * 8;
        const int row = rb + (lane >> 3);
        const int slot = (lane & 7) ^ (row & 7);
        gload16(&Bt[(size_t)(col0 + row) * D_ + kc + slot * 8], &Bsl[rb][0]);
      }
      __syncthreads();   // drains vmcnt (glLDS) + rendezvous
#pragma unroll
      for (int h = 0; h < 2; ++h) {
        half8 af[MT], bf[4];
#pragma unroll
        for (int mt = 0; mt < MT; ++mt) {
          const int r = wr + mt * 16 + m;
          af[mt] = *(const half8*)&Asl[r][(((4 * h + quad) ^ (r & 7)) * 8)];
        }
#pragma unroll
        for (int nt = 0; nt < 4; ++nt) {
          const int r = wc + nt * 16 + m;
          bf[nt] = *(const half8*)&Bsl[r][(((4 * h + quad) ^ (r & 7)) * 8)];
        }
#pragma unroll
        for (int mt = 0; mt < MT; ++mt)
#pragma unroll
          for (int nt = 0; nt < 4; ++nt)
            acc[mt][nt] = __builtin_amdgcn_mfma_f32_16x16x32_f16(
                af[mt], bf[nt], acc[mt][nt], 0, 0, 0);
      }
    }
  } else {
    _Float16 (*As)[72] = (_Float16 (*)[72])pool;
    _Float16 (*Bs)[72] = (_Float16 (*)[72])(pool + BM * 72);
    const int srow = tid >> 3, soff = (tid & 7) * 8;

    half8 pa16[MT];
    float4 pa32[MT][2];
    half8 pb[4];
#pragma unroll
    for (int i = 0; i < MT; ++i) {
      const size_t ar = (size_t)(row0 + srow + 32 * i) * D_ + soff;
      if (AF16) pa16[i] = *(const half8*)&A16[ar];
      else { pa32[i][0] = *(const float4*)&A32[ar];
             pa32[i][1] = *(const float4*)&A32[ar + 4]; }
    }
#pragma unroll
    for (int i = 0; i < 4; ++i)
      pb[i] = *(const half8*)&Bt[(size_t)(col0 + srow + 32 * i) * D_ + soff];

    for (int kt = 0; kt < D_ / 64; ++kt) {
      if (kt) __syncthreads();
#pragma unroll
      for (int i = 0; i < MT; ++i)
        *(half8*)&As[srow + 32 * i][soff] =
            AF16 ? pa16[i] : cvt_half8(pa32[i][0], pa32[i][1]);
#pragma unroll
      for (int i = 0; i < 4; ++i) *(half8*)&Bs[srow + 32 * i][soff] = pb[i];
      __syncthreads();
      if (kt < D_ / 64 - 1) {
        const int kc = (kt + 1) * 64 + soff;
#pragma unroll
        for (int i = 0; i < MT; ++i) {
          const size_t ar = (size_t)(row0 + srow + 32 * i) * D_ + kc;
          if (AF16) pa16[i] = *(const half8*)&A16[ar];
          else { pa32[i][0] = *(const float4*)&A32[ar];
                 pa32[i][1] = *(const float4*)&A32[ar + 4]; }
        }
#pragma unroll
        for (int i = 0; i < 4; ++i)
          pb[i] = *(const half8*)&Bt[(size_t)(col0 + srow + 32 * i) * D_ + kc];
      }
#pragma unroll
      for (int h = 0; h < 2; ++h) {
        half8 af[MT], bf[4];
#pragma unroll
        for (int mt = 0; mt < MT; ++mt)
          af[mt] = *(const half8*)&As[wr + mt * 16 + m][h * 32 + quad * 8];
#pragma unroll
        for (int nt = 0; nt < 4; ++nt)
          bf[nt] = *(const half8*)&Bs[wc + nt * 16 + m][h * 32 + quad * 8];
#pragma unroll
        for (int mt = 0; mt < MT; ++mt)
#pragma unroll
          for (int nt = 0; nt < 4; ++nt)
            acc[mt][nt] = __builtin_amdgcn_mfma_f32_16x16x32_f16(
                af[mt], bf[nt], acc[mt][nt], 0, 0, 0);
      }
    }
  }

  float bv[4];
#pragma unroll
  for (int nt = 0; nt < 4; ++nt)
    bv[nt] = bias[col0 + wc + nt * 16 + m] * bscale;

  if constexpr (OUTMODE == 2) {
    // ---- transposed V store: C tile -> LDS -> VhT[b][h][d][s] ----
    __syncthreads();   // all frag reads of As/Bs done before alias
    _Float16 (*Ct)[132] = (_Float16 (*)[132])pool;   // 128x132 <= pool
#pragma unroll
    for (int mt = 0; mt < MT; ++mt)
#pragma unroll
      for (int nt = 0; nt < 4; ++nt)
#pragma unroll
        for (int r = 0; r < 4; ++r)
          Ct[wr + mt * 16 + quad * 4 + r][wc + nt * 16 + m] =
              (_Float16)(acc[mt][nt][r] + bv[nt]);
    __syncthreads();
    const int c = tid & 127, sc = tid >> 7;          // col, s-half
    const int head = (col0 + c) >> 6, dd = (col0 + c) & 63;
    const int b = row0 >> 12;
    const int sbase = (row0 & (S_ - 1)) + sc * 64;
    _Float16* dst = (_Float16*)Cout +
        ((size_t)(b * H_ + head) * HD_ + dd) * S_ + sbase;
#pragma unroll
    for (int j = 0; j < 8; ++j) {
      half8 o;
#pragma unroll
      for (int e = 0; e < 8; ++e) o[e] = Ct[sc * 64 + j * 8 + e][c];
      *(half8*)&dst[j * 8] = o;
    }
  } else {
#pragma unroll
    for (int mt = 0; mt < MT; ++mt)
#pragma unroll
      for (int nt = 0; nt < 4; ++nt)
#pragma unroll
        for (int r = 0; r < 4; ++r) {
          const int row = row0 + wr + mt * 16 + quad * 4 + r;
          const int col = col0 + wc + nt * 16 + m;
          const float vout = acc[mt][nt][r] + bv[nt];
          if (OUTMODE == 1)
            ((_Float16*)Cout)[(size_t)row * D_ + col] = (_Float16)vout;
          else
            ((float*)Cout)[(size_t)row * D_ + col] = vout;
        }
  }
}

struct QkvPtrs { const float *A2, *b0, *b1, *b2; };

__global__ __launch_bounds__(256, 3) void qkv_gemm_kernel(
    QkvPtrs p, const _Float16* __restrict__ WT, _Float16* __restrict__ Cb,
    _Float16* __restrict__ VhT, const _Float16* __restrict__ Xh) {
  __shared__ alignas(16) _Float16 pool[(128 + 128) * 72];
  const int z = blockIdx.z;
  if (z == 2)
    gemm_body<false, 2, 128, false>(p.A2, WT + 2 * WELEM_, p.b2, VhT, 1.0f,
                                    pool, blockIdx.x, blockIdx.y, threadIdx.x);
  else
    gemm_body<true, 1, 128, true>(Xh + (size_t)z * NELEM_,
                                  WT + (size_t)z * WELEM_,
                                  z == 0 ? p.b0 : p.b1, Cb + (size_t)z * NELEM_,
                                  z == 0 ? 0.125f * LOG2E_ : 1.0f, pool,
                                  blockIdx.x, blockIdx.y, threadIdx.x);
}

// BM=32: 1024 blocks (grid 4x256) at 4 blocks/CU (r11: small win, keep).
__global__ __launch_bounds__(256, 4) void out_gemm_kernel(
    const _Float16* __restrict__ Oh, const _Float16* __restrict__ WpT,
    const float* __restrict__ bp, float* __restrict__ out) {
  __shared__ alignas(16) _Float16 pool[(32 + 128) * 72];
  gemm_body<true, 0, 32, true>(Oh, WpT, bp, out, 1.0f, pool, blockIdx.x,
                               blockIdx.y, threadIdx.x);
}

// ---------------------------------------------------------------------------
// MFMA flash attention, 32x32x16, fp16 I/O, split-K over keys.
// [r5-frozen structure: 95.8 us. r12's 2-acc cross-tile pipeline spilled
//  (live set ~140 VGPR > 128 cap -> 579 MB scratch writes, 270 us) and is
//  reverted per pre-commitment. Only surviving r12 element: fdot2 lpart
//  (correctness-proven there, zero register cost).]
// ---------------------------------------------------------------------------
__global__ __launch_bounds__(512, 4) void attn_mfma_kernel(
    const _Float16* __restrict__ Qg, const _Float16* __restrict__ Kg,
    const _Float16* __restrict__ VT, _Float16* __restrict__ Og) {
  __shared__ alignas(16) unsigned char smem[73728];
  _Float16 (*Ks)[2][64][72] =
      reinterpret_cast<_Float16 (*)[2][64][72]>(smem);          // [g][buf][key][d]
  _Float16 (*Vt)[2][64][72] =
      reinterpret_cast<_Float16 (*)[2][64][72]>(smem + 36864);  // [g][buf][d][key]
  float (*comb)[64][36] = (float (*)[64][36])smem;              // epilogue alias

  const int t = threadIdx.x;
  const int w = t >> 6;            // 0..7
  const int g = w >> 2;            // key-group
  const int wq = w & 3;            // wave within group
  const int lane = t & 63;
  const int li = lane & 31;        // q (B-side col) / key- or d-row (A-side)
  const int hl = lane >> 5;        // half-wave
  const int q0 = blockIdx.x * 128 + wq * 32;
  const int koff = g * (S_ / 2);
  const size_t base =
      (size_t)blockIdx.z * ((size_t)S_ * D_) + (size_t)blockIdx.y * HD_;
  const size_t vbase = (size_t)(blockIdx.z * H_ + blockIdx.y) * HD_ * S_;

  // Q B-frags: qb[ks][j] = Q[q0+li][16ks + 8hl + j]
  half8 qb[4];
#pragma unroll
  for (int ks = 0; ks < 4; ++ks)
    qb[ks] = *(const half8*)
        &Qg[base + (size_t)(q0 + li) * D_ + ks * 16 + hl * 8];

  floatx16 oacc[2];
#pragma unroll
  for (int i = 0; i < 16; ++i) { oacc[0][i] = 0.f; oacc[1][i] = 0.f; }
  float lpart = 0.f;
  const half2v one2 = {(_Float16)1.0f, (_Float16)1.0f};

  const int tg = t & 255;          // staging id within the group
  const int srow = tg >> 3, soff = (tg & 7) * 8;

  // stage group tile 0 into buf 0, prefetch tile 1 into regs
#pragma unroll
  for (int i = 0; i < 2; ++i) {
    *(half8*)&Ks[g][0][srow + 32 * i][soff] = *(const half8*)
        &Kg[base + (size_t)(koff + srow + 32 * i) * D_ + soff];
    *(half8*)&Vt[g][0][srow + 32 * i][soff] = *(const half8*)
        &VT[vbase + (size_t)(srow + 32 * i) * S_ + koff + soff];
  }
  half8 pk[2], pv[2];
#pragma unroll
  for (int i = 0; i < 2; ++i) {
    pk[i] = *(const half8*)
        &Kg[base + (size_t)(koff + 64 + srow + 32 * i) * D_ + soff];
    pv[i] = *(const half8*)
        &VT[vbase + (size_t)(srow + 32 * i) * S_ + koff + 64 + soff];
  }
  __syncthreads();

  constexpr int NT2 = S_ / 128;    // 32 tiles per key-group
  for (int kt = 0; kt < NT2; ++kt) {
    const int cur = kt & 1;
    if (kt + 1 < NT2) {
#pragma unroll
      for (int i = 0; i < 2; ++i) {
        *(half8*)&Ks[g][cur ^ 1][srow + 32 * i][soff] = pk[i];
        *(half8*)&Vt[g][cur ^ 1][srow + 32 * i][soff] = pv[i];
      }
      if (kt + 2 < NT2) {
        const int k2 = koff + (kt + 2) * 64;
#pragma unroll
        for (int i = 0; i < 2; ++i) {
          pk[i] = *(const half8*)
              &Kg[base + (size_t)(k2 + srow + 32 * i) * D_ + soff];
          pv[i] = *(const half8*)
              &VT[vbase + (size_t)(srow + 32 * i) * S_ + k2 + soff];
        }
      }
    }

    // ---- QK^T swapped: sacc[kt2] = S^T[32kt2 + key][q] ----
    floatx16 sacc[2];
#pragma unroll
    for (int i = 0; i < 16; ++i) { sacc[0][i] = 0.f; sacc[1][i] = 0.f; }
    __builtin_amdgcn_s_setprio(1);
#pragma unroll
    for (int ks = 0; ks < 4; ++ks) {
      const half8 ka0 = *(const half8*)&Ks[g][cur][li][ks * 16 + hl * 8];
      const half8 ka1 = *(const half8*)&Ks[g][cur][32 + li][ks * 16 + hl * 8];
      sacc[0] = __builtin_amdgcn_mfma_f32_32x32x16_f16(ka0, qb[ks],
                                                       sacc[0], 0, 0, 0);
      sacc[1] = __builtin_amdgcn_mfma_f32_32x32x16_f16(ka1, qb[ks],
                                                       sacc[1], 0, 0, 0);
    }
    __builtin_amdgcn_s_setprio(0);

    // ---- softmax + PV interleaved per kt2 half ----
    // source reg r of sacc[kt2] holds key-local (r&3)+8*(r>>2)+4*hl;
    // target frag(ks=2kt2+t2) half j needs key-local 16t2+8hl+j.
#pragma unroll
    for (int kt2 = 0; kt2 < 2; ++kt2) {
      unsigned dq[4][2];
#pragma unroll
      for (int rq = 0; rq < 4; ++rq)
#pragma unroll
        for (int pp = 0; pp < 2; ++pp) {
          const float e0 =
              exp2_hw(fminf(sacc[kt2][4 * rq + 2 * pp], SCLAMP_));
          const float e1 =
              exp2_hw(fminf(sacc[kt2][4 * rq + 2 * pp + 1], SCLAMP_));
          const fp16x2 h2 = __builtin_amdgcn_cvt_pkrtz(e0, e1);
#if __has_builtin(__builtin_amdgcn_fdot2)
          lpart = __builtin_amdgcn_fdot2(__builtin_bit_cast(half2v, h2),
                                         one2, lpart, false);
#else
          lpart += e0 + e1;
#endif
          dq[rq][pp] = __builtin_bit_cast(unsigned, h2);
        }
      half8 pf[2];
#pragma unroll
      for (int t2 = 0; t2 < 2; ++t2) {
        unsigned a0 = dq[2 * t2][0], b0 = dq[2 * t2 + 1][0];
        unsigned a1 = dq[2 * t2][1], b1 = dq[2 * t2 + 1][1];
        permswap32(a0, b0);
        permswap32(a1, b1);
        uintx4 u; u[0] = a0; u[1] = a1; u[2] = b0; u[3] = b1;
        pf[t2] = __builtin_bit_cast(half8, u);
      }
      // PV for this half: oacc += mfma(A=V^T frag, B=P frag) -> C[d][q]
      __builtin_amdgcn_s_setprio(1);
#pragma unroll
      for (int t2 = 0; t2 < 2; ++t2) {
        const int ks = 2 * kt2 + t2;
        const half8 va0 = *(const half8*)&Vt[g][cur][li][ks * 16 + hl * 8];
        const half8 va1 =
            *(const half8*)&Vt[g][cur][32 + li][ks * 16 + hl * 8];
        oacc[0] = __builtin_amdgcn_mfma_f32_32x32x16_f16(va0, pf[t2],
                                                         oacc[0], 0, 0, 0);
        oacc[1] = __builtin_amdgcn_mfma_f32_32x32x16_f16(va1, pf[t2],
                                                         oacc[1], 0, 0, 0);
      }
      __builtin_amdgcn_s_setprio(0);
    }

    __syncthreads();   // single barrier per tile (dbuf), common to both groups
  }

  // within-group full row-sum: lanes l and l+32 hold disjoint key subsets
  const float wsum = lpart + __shfl_xor(lpart, 32);

  // ---- cross-group combine (partials additive: clamp-softmax) ----
  if (g == 1) {
#pragma unroll
    for (int n = 0; n < 2; ++n)
#pragma unroll
      for (int c = 0; c < 4; ++c) {
        float4 f;
        f.x = oacc[n][4 * c + 0]; f.y = oacc[n][4 * c + 1];
        f.z = oacc[n][4 * c + 2]; f.w = oacc[n][4 * c + 3];
        *(float4*)&comb[wq][lane][n * 16 + 4 * c] = f;
      }
    comb[wq][lane][32] = wsum;
  }
  __syncthreads();
  if (g == 0) {
    const float linv = 1.0f / (wsum + comb[wq][lane][32]);
    // C[d][q]: lane q = li fixed; d = 32n + 8rq + (r&3) + 4hl
#pragma unroll
    for (int n = 0; n < 2; ++n)
#pragma unroll
      for (int rq = 0; rq < 4; ++rq) {
        const float4 cf = *(const float4*)&comb[wq][lane][n * 16 + 4 * rq];
        half4v o4;
        o4[0] = (_Float16)((oacc[n][4 * rq + 0] + cf.x) * linv);
        o4[1] = (_Float16)((oacc[n][4 * rq + 1] + cf.y) * linv);
        o4[2] = (_Float16)((oacc[n][4 * rq + 2] + cf.z) * linv);
        o4[3] = (_Float16)((oacc[n][4 * rq + 3] + cf.w) * linv);
        *(half4v*)&Og[base + (size_t)(q0 + li) * D_ +
                      n * 32 + 8 * rq + 4 * hl] = o4;
      }
  }
}

// ---------------------------------------------------------------------------
extern "C" void kernel_launch(void* const* d_in, const int* in_sizes, int n_in,
                              void* d_out, int out_size, void* d_ws,
                              size_t ws_size, hipStream_t stream) {
  const float* x  = (const float*)d_in[0];
  const float* y  = (const float*)d_in[1];
  const float* z  = (const float*)d_in[2];
  const float* Wq = (const float*)d_in[3];
  const float* bq = (const float*)d_in[4];
  const float* Wk = (const float*)d_in[5];
  const float* bk = (const float*)d_in[6];
  const float* Wv = (const float*)d_in[7];
  const float* bv = (const float*)d_in[8];
  const float* Wp = (const float*)d_in[9];
  const float* bp = (const float*)d_in[10];

  // workspace layout (44.04 MB, known-good footprint):
  //   WT  : 4 x WELEM                      (W^T fp16, q/k/v/p)
  //   Xh  : 2 x NELEM  (x,y fp16)  -- dead after qkv; Oh aliases it
  //   Qh, Kh, VhT : 1 x NELEM each
  _Float16* hws = (_Float16*)d_ws;
  _Float16* WT  = hws;
  _Float16* Xh  = WT + 4 * WELEM_;
  _Float16* Qh  = Xh + 2 * NELEM_;
  _Float16* Kh  = Qh + NELEM_;
  _Float16* VhT = Kh + NELEM_;
  _Float16* Oh  = Xh;                       // alias: Xh dead before attn

  PrepPtrs pp{Wq, Wk, Wv, Wp, x, y};
  prep_kernel<<<dim3(2048), 256, 0, stream>>>(pp, WT, Xh);

  QkvPtrs qp{z, bq, bk, bv};
  qkv_gemm_kernel<<<dim3(4, 64, 3), 256, 0, stream>>>(qp, WT, Qh, VhT, Xh);

  attn_mfma_kernel<<<dim3(S_ / 128, H_, B_), 512, 0, stream>>>(Qh, Kh, VhT, Oh);

  out_gemm_kernel<<<dim3(4, 256), 256, 0, stream>>>(Oh, WT + 3 * WELEM_, bp,
                                                    (float*)d_out);
}